// Round 7
// baseline (82.365 us; speedup 1.0000x reference)
//
#include <hip/hip_runtime.h>
#include <hip/hip_bf16.h>

// DLRM forward, bf16-MFMA, 6-launch pipeline (conversions redistributed).
// B=2048, dense 13, emb 26x100000x64, 27 feats -> 351 pairs,
// top MLP 415(->448)->1024->512->256->1 sigmoid.

#define BATCH 2048
#define VOCAB 100000
#define EMB 64
#define NSPARSE 26
#define NFEA 27
#define NPAIR 351
#define RLD 448            // padded R row stride (415 -> 448, %64==0)

typedef __attribute__((ext_vector_type(8))) __bf16 bf16x8;
typedef __attribute__((ext_vector_type(4))) float f32x4;
typedef __hip_bfloat16 bf16;

#define GLOAD16(g, l)                                                          \
    __builtin_amdgcn_global_load_lds(                                          \
        (const __attribute__((address_space(1))) unsigned int*)(g),            \
        (__attribute__((address_space(3))) unsigned int*)(l), 16, 0, 0)

template<int BK>
__device__ __forceinline__ int swz(int row, int s) {
    return (BK == 64) ? (s ^ (row & 7)) : (s ^ ((row >> 1) & 3));
}

// Weight convert+transpose tiles: dst[n][kp] = bf16(src[k][n]), zero-pad k>=K.
// Grid-strided over 32x32 tiles; callable from any 256-thread kernel.
__device__ __forceinline__ void conv_tiles(
    const float* __restrict__ src, bf16* __restrict__ dst,
    int K, int N, int Kp, int tiles, int gridsz, float (*Ts)[33])
{
    const int tx = threadIdx.x & 31, ty = threadIdx.x >> 5;
    for (int tile = blockIdx.x; tile < tiles; tile += gridsz) {
        const int nbn = N >> 5;
        const int tk = tile / nbn, tn = tile % nbn;
        __syncthreads();
#pragma unroll
        for (int rr = 0; rr < 4; ++rr) {
            const int k = tk * 32 + ty + rr * 8, n = tn * 32 + tx;
            Ts[ty + rr * 8][tx] = (k < K) ? src[(size_t)k * N + n] : 0.f;
        }
        __syncthreads();
#pragma unroll
        for (int rr = 0; rr < 4; ++rr) {
            const int n = tn * 32 + ty + rr * 8, kp = tk * 32 + tx;
            dst[(size_t)n * Kp + kp] = __float2bfloat16(Ts[tx][ty + rr * 8]);
        }
    }
}

// ---------------------------------------------------------------------------
// bf16 MFMA GEMM. 4 waves (WR x WC), wave sub-tile (MREP*16) x (NREP*16).
// MODE 0: A bf16, C = relu(A@Wt^T + b).  Pipelined when PA+PB==4 (depth-2,
//         3 LDS bufs, counted vmcnt(8)); else single-buffered.
// MODE 1: layer-0. A = f32 dense[M][13] padded to K=32; W = f32 bw0[13][N]
//         transposed+converted in-kernel (VALU stage). Single K-step.
// MODE 2: full-width output layer + fused final dot: out[row] =
//         sigmoid(dot(relu(A@Wt^T+b), w3) + b3). No C write. BN must == N.
// DOCONV: after epilogue, run conv_tiles(csrc->cdst) grid-strided.
// ---------------------------------------------------------------------------
template<int BK, int WR, int WC, int MREP, int NREP, int MODE, bool DOCONV>
__global__ __launch_bounds__(256) void gemm_bf16(
    const void* __restrict__ Araw, const void* __restrict__ Wraw,
    const float* __restrict__ bias, bf16* __restrict__ C,
    int M, int N, int K, int ldC,
    const float* __restrict__ csrc, bf16* __restrict__ cdst,
    int cK, int cN, int cKp, int cTiles,
    const float* __restrict__ w3, const float* __restrict__ b3,
    float* __restrict__ outv)
{
    constexpr int BM    = WR * MREP * 16;
    constexpr int BN    = WC * NREP * 16;
    constexpr int ROWB  = BK * 2;
    constexpr int SLOTS = BK / 8;
    constexpr int KKS   = BK / 32;
    constexpr int PA    = BM * SLOTS / 256;
    constexpr int PB    = BN * SLOTS / 256;
    constexpr bool PIPE = (MODE == 0) && (PA + PB == 4);

    const int t   = threadIdx.x;
    const int nbn = N / BN;
    const int bm  = blockIdx.x / nbn;
    const int bn  = blockIdx.x % nbn;
    const int row0 = bm * BM, n0 = bn * BN;

    const int wid  = t >> 6, lane = t & 63;
    const int wr   = wid / WC, wc = wid % WC;
    const int lr   = lane & 15;
    const int q    = lane >> 4;
    const int sslot = t % SLOTS;

    f32x4 acc[MREP][NREP] = {};

    if constexpr (MODE == 1) {
        // ---- layer-0: K=32 single step, VALU-stage A (f32 pad) and B (f32^T)
        __shared__ __align__(16) bf16 As[BM * 32];
        __shared__ __align__(16) bf16 Bs[BN * 32];
        const float* Df = (const float*)Araw;
        const float* Wf = (const float*)Wraw;   // [13][N]
#pragma unroll
        for (int idx = t; idx < BM * 32; idx += 256) {
            const int r = idx >> 5, c = idx & 31;
            const float v = (c < 13) ? Df[(size_t)(row0 + r) * 13 + c] : 0.f;
            As[r * 32 + swz<32>(r, c >> 3) * 8 + (c & 7)] = __float2bfloat16(v);
        }
#pragma unroll
        for (int idx = t; idx < BN * 32; idx += 256) {
            const int r = idx >> 5, c = idx & 31;   // r = n-row, c = k
            const float v = (c < 13) ? Wf[(size_t)c * N + n0 + r] : 0.f;
            Bs[r * 32 + swz<32>(r, c >> 3) * 8 + (c & 7)] = __float2bfloat16(v);
        }
        __syncthreads();

        bf16x8 af[MREP], bfr[NREP];
#pragma unroll
        for (int m = 0; m < MREP; ++m) {
            const int r = wr * MREP * 16 + 16 * m + lr;
            af[m] = *(const bf16x8*)((const char*)As + r * 64 +
                                     swz<32>(r, q) * 16);
        }
#pragma unroll
        for (int n = 0; n < NREP; ++n) {
            const int r = wc * NREP * 16 + 16 * n + lr;
            bfr[n] = *(const bf16x8*)((const char*)Bs + r * 64 +
                                      swz<32>(r, q) * 16);
        }
#pragma unroll
        for (int m = 0; m < MREP; ++m)
#pragma unroll
            for (int n = 0; n < NREP; ++n)
                acc[m][n] = __builtin_amdgcn_mfma_f32_16x16x32_bf16(
                    af[m], bfr[n], acc[m][n], 0, 0, 0);
        __syncthreads();
    } else if constexpr (PIPE) {
        // ---- depth-2 counted-vmcnt pipeline, 3 buffers (R6-verified) ----
        __shared__ __align__(16) bf16 As[3][BM * BK];
        __shared__ __align__(16) bf16 Bs[3][BN * BK];
        const bf16* Wt = (const bf16*)Wraw;

        const bf16* Ab[PA];
        const bf16* Bb[PB];
#pragma unroll
        for (int p = 0; p < PA; ++p) {
            const int r = (p * 256 + t) / SLOTS;
            Ab[p] = (const bf16*)Araw + (size_t)(row0 + r) * K +
                    swz<BK>(r, sslot) * 8;
        }
#pragma unroll
        for (int p = 0; p < PB; ++p) {
            const int r = (p * 256 + t) / SLOTS;
            Bb[p] = Wt + (size_t)(n0 + r) * K + swz<BK>(r, sslot) * 8;
        }

        const int nsteps = K / BK;
        auto stage = [&](int s) {
            const int buf = s % 3;
            const int k0  = (s < nsteps ? s : nsteps - 1) * BK;
#pragma unroll
            for (int p = 0; p < PA; ++p)
                GLOAD16(Ab[p] + k0, (char*)As[buf] + (p * 256 + t) * 16);
#pragma unroll
            for (int p = 0; p < PB; ++p)
                GLOAD16(Bb[p] + k0, (char*)Bs[buf] + (p * 256 + t) * 16);
        };

        stage(0);
        stage(1);

        for (int ks = 0; ks < nsteps; ++ks) {
            stage(ks + 2);

            asm volatile("s_waitcnt vmcnt(8)" ::: "memory");
            __builtin_amdgcn_s_barrier();
            __builtin_amdgcn_sched_barrier(0);

            const int buf = ks % 3;
            bf16x8 af[KKS][MREP], bfr[KKS][NREP];
#pragma unroll
            for (int kk = 0; kk < KKS; ++kk) {
#pragma unroll
                for (int m = 0; m < MREP; ++m) {
                    const int r = wr * MREP * 16 + 16 * m + lr;
                    af[kk][m] = *(const bf16x8*)((const char*)As[buf] + r * ROWB +
                                                 swz<BK>(r, kk * 4 + q) * 16);
                }
#pragma unroll
                for (int n = 0; n < NREP; ++n) {
                    const int r = wc * NREP * 16 + 16 * n + lr;
                    bfr[kk][n] = *(const bf16x8*)((const char*)Bs[buf] + r * ROWB +
                                                  swz<BK>(r, kk * 4 + q) * 16);
                }
            }
#pragma unroll
            for (int kk = 0; kk < KKS; ++kk)
#pragma unroll
                for (int m = 0; m < MREP; ++m)
#pragma unroll
                    for (int n = 0; n < NREP; ++n)
                        acc[m][n] = __builtin_amdgcn_mfma_f32_16x16x32_bf16(
                            af[kk][m], bfr[kk][n], acc[m][n], 0, 0, 0);

            asm volatile("s_waitcnt lgkmcnt(0)" ::: "memory");
            __builtin_amdgcn_s_barrier();
            __builtin_amdgcn_sched_barrier(0);
        }
    } else {
        // ---- single-buffered (R3-verified) ----
        __shared__ __align__(16) bf16 As[BM * BK];
        __shared__ __align__(16) bf16 Bs[BN * BK];
        const bf16* Wt = (const bf16*)Wraw;

        const bf16* Ab[PA];
        const bf16* Bb[PB];
#pragma unroll
        for (int p = 0; p < PA; ++p) {
            const int r = (p * 256 + t) / SLOTS;
            Ab[p] = (const bf16*)Araw + (size_t)(row0 + r) * K +
                    swz<BK>(r, sslot) * 8;
        }
#pragma unroll
        for (int p = 0; p < PB; ++p) {
            const int r = (p * 256 + t) / SLOTS;
            Bb[p] = Wt + (size_t)(n0 + r) * K + swz<BK>(r, sslot) * 8;
        }

        for (int k0 = 0; k0 < K; k0 += BK) {
#pragma unroll
            for (int p = 0; p < PA; ++p)
                GLOAD16(Ab[p] + k0, (char*)As + (p * 256 + t) * 16);
#pragma unroll
            for (int p = 0; p < PB; ++p)
                GLOAD16(Bb[p] + k0, (char*)Bs + (p * 256 + t) * 16);
            __syncthreads();

            bf16x8 af[KKS][MREP], bfr[KKS][NREP];
#pragma unroll
            for (int kk = 0; kk < KKS; ++kk) {
#pragma unroll
                for (int m = 0; m < MREP; ++m) {
                    const int r = wr * MREP * 16 + 16 * m + lr;
                    af[kk][m] = *(const bf16x8*)((const char*)As + r * ROWB +
                                                 swz<BK>(r, kk * 4 + q) * 16);
                }
#pragma unroll
                for (int n = 0; n < NREP; ++n) {
                    const int r = wc * NREP * 16 + 16 * n + lr;
                    bfr[kk][n] = *(const bf16x8*)((const char*)Bs + r * ROWB +
                                                  swz<BK>(r, kk * 4 + q) * 16);
                }
            }
#pragma unroll
            for (int kk = 0; kk < KKS; ++kk)
#pragma unroll
                for (int m = 0; m < MREP; ++m)
#pragma unroll
                    for (int n = 0; n < NREP; ++n)
                        acc[m][n] = __builtin_amdgcn_mfma_f32_16x16x32_bf16(
                            af[kk][m], bfr[kk][n], acc[m][n], 0, 0, 0);
            __syncthreads();
        }
    }

    // ---- epilogue ----
    if constexpr (MODE == 2) {
        __shared__ float rsum[BM];
        for (int i = t; i < BM; i += 256) rsum[i] = 0.f;
        __syncthreads();
#pragma unroll
        for (int n = 0; n < NREP; ++n) {
            const int col = n0 + wc * NREP * 16 + 16 * n + lr;
            const float bv = bias[col];
            const float wv = w3[col];
#pragma unroll
            for (int m = 0; m < MREP; ++m) {
#pragma unroll
                for (int i = 0; i < 4; ++i) {
                    const int rl = wr * MREP * 16 + 16 * m + q * 4 + i;
                    const float v = fmaxf(acc[m][n][i] + bv, 0.f);
                    atomicAdd(&rsum[rl], v * wv);
                }
            }
        }
        __syncthreads();
        if (t < BM)
            outv[row0 + t] = 1.f / (1.f + expf(-(rsum[t] + b3[0])));
    } else {
#pragma unroll
        for (int n = 0; n < NREP; ++n) {
            const int col = n0 + wc * NREP * 16 + 16 * n + lr;
            const float bv = bias[col];
#pragma unroll
            for (int m = 0; m < MREP; ++m) {
#pragma unroll
                for (int i = 0; i < 4; ++i) {
                    const int row = row0 + wr * MREP * 16 + 16 * m + q * 4 + i;
                    float v = acc[m][n][i] + bv;
                    v = fmaxf(v, 0.f);
                    C[(size_t)row * ldC + col] = __float2bfloat16(v);
                }
            }
        }
    }

    if constexpr (DOCONV) {
        __shared__ float Ts[32][33];
        conv_tiles(csrc, cdst, cK, cN, cKp, cTiles, gridDim.x, Ts);
    }
}

// ---------------------------------------------------------------------------
// Fused: bot = relu(h1 @ bw2 + bb2) + embedding gather + pairwise dots
//        + top-MLP weight conversions (hidden under gather latency).
// 2 batch rows per block, 1024 blocks, ~25 KB LDS.
// ---------------------------------------------------------------------------
__global__ __launch_bounds__(256) void interact_kernel(
    const bf16* __restrict__ h1,    // [B][256]
    const bf16* __restrict__ bw2t,  // [64][256] = bw2^T
    const float* __restrict__ bb2,
    const int* __restrict__ cat_idx,
    const float* __restrict__ tables,
    bf16* __restrict__ R,
    const float* __restrict__ tw0, bf16* __restrict__ tw0t,
    const float* __restrict__ tw1, bf16* __restrict__ tw1t,
    const float* __restrict__ tw2, bf16* __restrict__ tw2t)
{
    __shared__ float T[2][NFEA][EMB + 1];
    __shared__ bf16  h1s[2][256];
    __shared__ float Ts[32][33];

    const int b0 = blockIdx.x * 2;
    const int t  = threadIdx.x;

    if (t < 64) {
        const int r = t >> 5, c = (t & 31) * 8;
        *(bf16x8*)&h1s[r][c] =
            *(const bf16x8*)&h1[(size_t)(b0 + r) * 256 + c];
    }

    for (int l = t; l < 2 * NSPARSE * 16; l += 256) {
        const int r   = l / (NSPARSE * 16);
        const int rem = l % (NSPARSE * 16);
        const int j   = rem >> 4, c = (rem & 15) * 4;
        const int idx = cat_idx[(b0 + r) * NSPARSE + j];
        const float4 v =
            *(const float4*)&tables[((size_t)j * VOCAB + idx) * EMB + c];
        float* dst = &T[r][j + 1][c];
        dst[0] = v.x; dst[1] = v.y; dst[2] = v.z; dst[3] = v.w;
    }

    for (int z = t; z < 2 * (RLD - 415); z += 256) {
        const int r = z / (RLD - 415), c = z % (RLD - 415);
        R[(size_t)(b0 + r) * RLD + 415 + c] = __float2bfloat16(0.f);
    }
    __syncthreads();

    if (t < 128) {
        const int r = t >> 6, n = t & 63;
        float s = bb2[n];
        const bf16* wrow = bw2t + (size_t)n * 256;
#pragma unroll 8
        for (int k = 0; k < 256; k += 8) {
            const bf16x8 hv = *(const bf16x8*)&h1s[r][k];
            const bf16x8 wv = *(const bf16x8*)&wrow[k];
#pragma unroll
            for (int u = 0; u < 8; ++u)
                s += (float)hv[u] * (float)wv[u];
        }
        s = fmaxf(s, 0.f);
        T[r][0][n] = s;
        R[(size_t)(b0 + r) * RLD + n] = __float2bfloat16(s);
    }
    __syncthreads();

    for (int task = t; task < 2 * NPAIR; task += 256) {
        const int r = task / NPAIR, p = task % NPAIR;
        int i = (int)((1.0f + sqrtf(1.0f + 8.0f * (float)p)) * 0.5f);
        while (i * (i - 1) / 2 > p) --i;
        while ((i + 1) * i / 2 <= p) ++i;
        const int j = p - i * (i - 1) / 2;
        float s = 0.f;
#pragma unroll 16
        for (int k = 0; k < EMB; ++k) s += T[r][i][k] * T[r][j][k];
        R[(size_t)(b0 + r) * RLD + EMB + p] = __float2bfloat16(s);
    }

    // top-MLP weight conversions (consumed by later kernels)
    conv_tiles(tw0, tw0t, 415,  1024, RLD,  (RLD >> 5) * (1024 >> 5), gridDim.x, Ts);
    conv_tiles(tw1, tw1t, 1024, 512,  1024, (1024 >> 5) * (512 >> 5), gridDim.x, Ts);
    conv_tiles(tw2, tw2t, 512,  256,  512,  (512 >> 5) * (256 >> 5),  gridDim.x, Ts);
}

// ---------------------------------------------------------------------------
extern "C" void kernel_launch(void* const* d_in, const int* in_sizes, int n_in,
                              void* d_out, int out_size, void* d_ws, size_t ws_size,
                              hipStream_t stream)
{
    const float* dense   = (const float*)d_in[0];
    const int*   cat_idx = (const int*)  d_in[1];
    const float* tables  = (const float*)d_in[2];
    const float* bw0 = (const float*)d_in[3];
    const float* bb0 = (const float*)d_in[4];
    const float* bw1 = (const float*)d_in[5];
    const float* bb1 = (const float*)d_in[6];
    const float* bw2 = (const float*)d_in[7];
    const float* bb2 = (const float*)d_in[8];
    const float* tw0 = (const float*)d_in[9];
    const float* tb0 = (const float*)d_in[10];
    const float* tw1 = (const float*)d_in[11];
    const float* tb1 = (const float*)d_in[12];
    const float* tw2 = (const float*)d_in[13];
    const float* tb2 = (const float*)d_in[14];
    const float* tw3 = (const float*)d_in[15];
    const float* tb3 = (const float*)d_in[16];

    bf16* p = (bf16*)d_ws;
    bf16* h0   = p; p += (size_t)BATCH * 512;
    bf16* h1   = p; p += (size_t)BATCH * 256;
    bf16* R    = p; p += (size_t)BATCH * RLD;
    bf16* r0   = p; p += (size_t)BATCH * 1024;
    bf16* r1   = p; p += (size_t)BATCH * 512;
    bf16* bw1t = p; p += 256 * 512;
    bf16* bw2t = p; p += 64 * 256;
    bf16* tw0t = p; p += 1024 * RLD;
    bf16* tw1t = p; p += 512 * 1024;
    bf16* tw2t = p; p += 256 * 512;
    float* out = (float*)d_out;

    // 1) layer-0 (self-converts bw0) + bw1 conversion for layer-1
    gemm_bf16<32, 2, 2, 2, 2, 1, true>
        <<<(BATCH / 64) * (512 / 64), 256, 0, stream>>>(
        dense, bw0, bb0, h0, BATCH, 512, 32, 512,
        bw1, bw1t, 512, 256, 512, (512 >> 5) * (256 >> 5),
        nullptr, nullptr, nullptr);

    // 2) layer-1 (pipelined) + bw2 conversion
    gemm_bf16<64, 2, 2, 2, 2, 0, true>
        <<<(BATCH / 64) * (256 / 64), 256, 0, stream>>>(
        h0, bw1t, bb1, h1, BATCH, 256, 512, 256,
        bw2, bw2t, 256, 64, 256, (256 >> 5) * (64 >> 5),
        nullptr, nullptr, nullptr);

    // 3) bot + gather + interaction + tw0/tw1/tw2 conversions
    interact_kernel<<<BATCH / 2, 256, 0, stream>>>(
        h1, bw2t, bb2, cat_idx, tables, R,
        tw0, tw0t, tw1, tw1t, tw2, tw2t);

    // 4) top-0 (pipelined)
    gemm_bf16<64, 2, 2, 2, 2, 0, false>
        <<<(BATCH / 64) * (1024 / 64), 256, 0, stream>>>(
        R, tw0t, tb0, r0, BATCH, 1024, RLD, 1024,
        nullptr, nullptr, 0, 0, 0, 0, nullptr, nullptr, nullptr);

    // 5) top-1 (pipelined)
    gemm_bf16<64, 2, 2, 2, 2, 0, false>
        <<<(BATCH / 64) * (512 / 64), 256, 0, stream>>>(
        r0, tw1t, tb1, r1, BATCH, 512, 1024, 512,
        nullptr, nullptr, 0, 0, 0, 0, nullptr, nullptr, nullptr);

    // 6) top-2 full-width + fused sigmoid-dot output
    gemm_bf16<64, 1, 4, 2, 4, 2, false>
        <<<(BATCH / 32) * (256 / 256), 256, 0, stream>>>(
        r1, tw2t, tb2, nullptr, BATCH, 256, 512, 256,
        nullptr, nullptr, 0, 0, 0, 0, tw3, tb3, out);
}